// Round 23
// baseline (300.467 us; speedup 1.0000x reference)
//
#include <hip/hip_runtime.h>
#include <hip/hip_bf16.h>
#include <stdint.h>

#define NMET 20000
#define NRXN 40000
#define DDIM 256
#define CDIM 64
#define ROWB 512   // bytes per feature row (256 bf16)

typedef __attribute__((ext_vector_type(8))) short bf16x8;
typedef __attribute__((ext_vector_type(4))) float f32x4;

typedef __attribute__((address_space(1))) const void gvoid_t;
typedef __attribute__((address_space(3))) void lvoid_t;

// ---------------- threefry2x32 (exact JAX semantics) ----------------
__host__ __device__ inline void tf2x32(unsigned k0, unsigned k1,
                                       unsigned x0, unsigned x1,
                                       unsigned &o0, unsigned &o1) {
  unsigned ks2 = k0 ^ k1 ^ 0x1BD11BDAu;
#define TFR(r) { x0 += x1; x1 = (x1 << r) | (x1 >> (32 - r)); x1 ^= x0; }
  x0 += k0; x1 += k1;
  TFR(13) TFR(15) TFR(26) TFR(6)
  x0 += k1; x1 += ks2 + 1u;
  TFR(17) TFR(29) TFR(16) TFR(24)
  x0 += ks2; x1 += k0 + 2u;
  TFR(13) TFR(15) TFR(26) TFR(6)
  x0 += k0; x1 += k1 + 3u;
  TFR(17) TFR(29) TFR(16) TFR(24)
  x0 += k1; x1 += ks2 + 4u;
  TFR(13) TFR(15) TFR(26) TFR(6)
  x0 += ks2; x1 += k0 + 5u;
#undef TFR
  o0 = x0; o1 = x1;
}

__device__ inline unsigned short f2bbits(float f) {
  __hip_bfloat16 h = __float2bfloat16(f);
  return *reinterpret_cast<unsigned short*>(&h);
}
__device__ inline float b2f(unsigned short u) {
  unsigned v = (unsigned)u << 16;
  return __uint_as_float(v);
}

// 16-lane row sum via DPP row_ror (VALU pipe, no DS): every lane gets the row total.
__device__ inline float rowsum16(float v) {
  int t;
  t = __builtin_amdgcn_update_dpp(0, __float_as_int(v), 0x128, 0xF, 0xF, false);  // row_ror:8
  v += __int_as_float(t);
  t = __builtin_amdgcn_update_dpp(0, __float_as_int(v), 0x124, 0xF, 0xF, false);  // row_ror:4
  v += __int_as_float(t);
  t = __builtin_amdgcn_update_dpp(0, __float_as_int(v), 0x122, 0xF, 0xF, false);  // row_ror:2
  v += __int_as_float(t);
  t = __builtin_amdgcn_update_dpp(0, __float_as_int(v), 0x121, 0xF, 0xF, false);  // row_ror:1
  v += __int_as_float(t);
  return v;
}

// ---------------- prep: hist3 + cvt(x_met) + cvt(x_rxn) + wtrans, one dispatch ----------------
#define CVT_A_BLK 2500   // NMET*DDIM/8/256
#define CVT_B_BLK 5000   // NRXN*DDIM/8/256
__global__ __launch_bounds__(256) void prep_all(
    const float* __restrict__ x_met, __hip_bfloat16* __restrict__ xmb,
    const float* __restrict__ x_rxn, __hip_bfloat16* __restrict__ xrb,
    const float* w0, const float* w1, const float* w2, const float* w3,
    const float* w4, const float* w5, const float* w6, const float* w7,
    __hip_bfloat16* o0, __hip_bfloat16* o1, __hip_bfloat16* o2, __hip_bfloat16* o3,
    __hip_bfloat16* o4, __hip_bfloat16* o5, __hip_bfloat16* o6, __hip_bfloat16* o7,
    const int* __restrict__ hd0, const int* __restrict__ hd1, const int* __restrict__ hd2,
    int E, int* __restrict__ hc0, int* __restrict__ hc1, int* __restrict__ hc2,
    int histB) {
  __shared__ float ts[32][33];
  int bid = blockIdx.x;
  // ---- hist role (first 3*histB blocks) ----
  if (bid < 3 * histB) {
    int rel = bid / histB;
    int i = (bid - rel * histB) * 256 + threadIdx.x;
    if (i < E) {
      if (rel == 0) atomicAdd(&hc0[hd0[i]], 1);
      else if (rel == 1) atomicAdd(&hc1[hd1[i]], 1);
      else atomicAdd(&hc2[hd2[i]], 1);
    }
    return;
  }
  bid -= 3 * histB;
  if (bid < CVT_A_BLK + CVT_B_BLK) {
    const float* in; __hip_bfloat16* out; int n;
    if (bid < CVT_A_BLK) { in = x_met; out = xmb; n = NMET * DDIM; }
    else { in = x_rxn; out = xrb; n = NRXN * DDIM; bid -= CVT_A_BLK; }
    int i = (bid * 256 + threadIdx.x) * 8;
    if (i >= n) return;
    float4 va = *reinterpret_cast<const float4*>(in + i);
    float4 vb = *reinterpret_cast<const float4*>(in + i + 4);
    bf16x8 o;
    o[0] = (short)f2bbits(va.x); o[1] = (short)f2bbits(va.y);
    o[2] = (short)f2bbits(va.z); o[3] = (short)f2bbits(va.w);
    o[4] = (short)f2bbits(vb.x); o[5] = (short)f2bbits(vb.y);
    o[6] = (short)f2bbits(vb.z); o[7] = (short)f2bbits(vb.w);
    *reinterpret_cast<bf16x8*>(out + i) = o;
    return;
  }
  int t = bid - (CVT_A_BLK + CVT_B_BLK);
  int z = t >> 6, tt = t & 63;
  const float* w; __hip_bfloat16* o; int Ncols;
  switch (z) {
    case 0: w = w0; o = o0; Ncols = 256; break;
    case 1: w = w1; o = o1; Ncols = 256; break;
    case 2: w = w2; o = o2; Ncols = 256; break;
    case 3: w = w3; o = o3; Ncols = 256; break;
    case 4: w = w4; o = o4; Ncols = 256; break;
    case 5: w = w5; o = o5; Ncols = 256; break;
    case 6: w = w6; o = o6; Ncols = 64; break;
    default: w = w7; o = o7; Ncols = 64; break;
  }
  int ntile = Ncols / 32;
  if (tt >= ntile * 8) return;  // K=256 -> 8 k-tiles
  int tn = tt % ntile, tk = tt / ntile;
  int tx = threadIdx.x & 31, ty = threadIdx.x >> 5;
#pragma unroll
  for (int r = ty; r < 32; r += 8)
    ts[r][tx] = w[(size_t)(tk * 32 + r) * Ncols + tn * 32 + tx];
  __syncthreads();
#pragma unroll
  for (int r = ty; r < 32; r += 8)
    o[(size_t)(tn * 32 + r) * 256 + tk * 32 + tx] = __float2bfloat16(ts[tx][r]);
}

// ---------------- scatter args (fused into gemm dispatch, tail blocks) ----------------
struct ScatArgs {
  const int *s0, *d0, *s1, *d1, *s2, *d2;
  int E;
  int *u0, *u1, *u2, *e0, *e1, *e2;
};

// ---------------- tiled multi-GEMM + tail scatter: 128x128 tile, BK=64, LDS + XCD swizzle ----------------
struct TDesc {
  const __hip_bfloat16* X;   // [M,256]
  const __hip_bfloat16* W;   // Wt[N,256]
  const float* bias;
  __hip_bfloat16* Yb;        // bf16 out (or null)
  float* Yf;                 // f32 out (or null)
  int M, N, nt, blocks;      // nt = ceil(N/128), blocks = ceil(M/128)*nt
};
struct TD8 { TDesc g[8]; };

__global__ __launch_bounds__(256) void gemm_tiled8(TD8 gd, int ng, int total,
                                                   ScatArgs sa, int scatB) {
  __shared__ __align__(16) char As[16384];   // A tile [128][64] bf16, swizzled groups
  __shared__ __align__(16) char Bs[16384];   // B tile [128][64] bf16
  int b = blockIdx.x;
  // ---- scatter role: TAIL blocks (launch after GEMM fills the machine) ----
  if (b >= total) {
    int sb = b - total;
    int rel = sb / scatB;
    int i = (sb - rel * scatB) * 256 + threadIdx.x;
    if (i < sa.E) {
      if (rel == 0)      { int pos = atomicAdd(&sa.u0[sa.d0[i]], 1); sa.e0[pos] = sa.s0[i] * ROWB; }
      else if (rel == 1) { int pos = atomicAdd(&sa.u1[sa.d1[i]], 1); sa.e1[pos] = sa.s1[i] * ROWB; }
      else               { int pos = atomicAdd(&sa.u2[sa.d2[i]], 1); sa.e2[pos] = sa.s2[i] * ROWB; }
    }
    return;
  }
  // T1: bijective XCD-chunked remap (m204 form) over the gemm block range.
  int q = total >> 3, r = total & 7;
  int xcd = b & 7, idx = b >> 3;
  int bid = (xcd < r) ? (xcd * (q + 1) + idx)
                      : (r * (q + 1) + (xcd - r) * q + idx);
  int di = 0;
  while (di < ng && bid >= gd.g[di].blocks) { bid -= gd.g[di].blocks; ++di; }
  if (di >= ng) return;
  TDesc g = gd.g[di];
  int mrow = bid / g.nt, ntile = bid - mrow * g.nt;
  int m0 = mrow * 128, n0 = ntile * 128;
  int tid = threadIdx.x, wave = tid >> 6, lane = tid & 63;
  int lr = lane & 15, lk = lane >> 4;
  int wm = wave >> 1, wn = wave & 1;
  int brows = g.N - n0; if (brows > 128) brows = 128;
  int bch = brows >> 3;               // B chunks of 8 rows (1024B)
  int lrow = lane >> 3;               // row within chunk (0..7)
  int gsw = ((lane & 7) ^ lrow) * 8;  // inverse-swizzled source col (bf16) within 64

  f32x4 acc[4][4] = {};
  for (int kt = 0; kt < 4; ++kt) {
    for (int c = wave; c < 16; c += 4) {
      int row = m0 + c * 8 + lrow;
      if (row > g.M - 1) row = g.M - 1;
      const void* src = g.X + (size_t)row * DDIM + kt * 64 + gsw;
      __builtin_amdgcn_global_load_lds((gvoid_t*)src, (lvoid_t*)(As + c * 1024), 16, 0, 0);
    }
    for (int c = wave; c < bch; c += 4) {
      int row = n0 + c * 8 + lrow;
      const void* src = g.W + (size_t)row * DDIM + kt * 64 + gsw;
      __builtin_amdgcn_global_load_lds((gvoid_t*)src, (lvoid_t*)(Bs + c * 1024), 16, 0, 0);
    }
    __syncthreads();
#pragma unroll
    for (int kk = 0; kk < 2; ++kk) {
      bf16x8 a[4], b2[4];
#pragma unroll
      for (int m = 0; m < 4; ++m) {
        int row = wm * 64 + m * 16 + lr;
        int grp = (kk * 4 + lk) ^ (lr & 7);
        a[m] = *reinterpret_cast<const bf16x8*>(As + row * 128 + grp * 16);
      }
#pragma unroll
      for (int n = 0; n < 4; ++n) {
        int row = wn * 64 + n * 16 + lr;
        int grp = (kk * 4 + lk) ^ (lr & 7);
        b2[n] = *reinterpret_cast<const bf16x8*>(Bs + row * 128 + grp * 16);
      }
#pragma unroll
      for (int m = 0; m < 4; ++m)
#pragma unroll
        for (int n = 0; n < 4; ++n)
          acc[m][n] = __builtin_amdgcn_mfma_f32_16x16x32_bf16(a[m], b2[n], acc[m][n], 0, 0, 0);
    }
    __syncthreads();
  }
  bool isb = (g.Yb != nullptr);
#pragma unroll
  for (int m = 0; m < 4; ++m) {
#pragma unroll
    for (int rr = 0; rr < 4; ++rr) {
      int row = m0 + wm * 64 + m * 16 + lk * 4 + rr;
      if (row >= g.M) continue;
#pragma unroll
      for (int n = 0; n < 4; ++n) {
        int cg = n0 + wn * 64 + n * 16 + lr;
        if (cg >= g.N) continue;
        float v = acc[m][n][rr] + g.bias[cg];
        if (isb) g.Yb[(size_t)row * g.N + cg] = __float2bfloat16(v);
        else     g.Yf[(size_t)row * g.N + cg] = v;
      }
    }
  }
}

// ---------------- range allocation via atomic cursor ----------------
__global__ __launch_bounds__(256) void alloc3(
    const int* __restrict__ c0, const int* __restrict__ c1, const int* __restrict__ c2,
    int* __restrict__ o0, int* __restrict__ o1, int* __restrict__ o2,
    int* __restrict__ u0, int* __restrict__ u1, int* __restrict__ u2,
    int* __restrict__ cursors, int n0, int n1, int n2) {
  int rel = blockIdx.y;
  int i = blockIdx.x * 256 + threadIdx.x;
  const int* c = (rel == 0) ? c0 : (rel == 1) ? c1 : c2;
  int* o = (rel == 0) ? o0 : (rel == 1) ? o1 : o2;
  int* u = (rel == 0) ? u0 : (rel == 1) ? u1 : u2;
  int n = (rel == 0) ? n0 : (rel == 1) ? n1 : n2;
  if (i >= n) return;
  int cc = c[i];
  int pos = atomicAdd(&cursors[rel], cc);
  o[i] = pos; u[i] = pos;
}

// ---------------- GAT wave body ----------------
// No-max softmax: scores bounded (|p| < ~6) so exp(p) is fp32-safe; identical result.
// Score reduce uses DPP row_ror rowsum16 (VALU pipe) instead of shfl_xor (DS pipe).
struct GatRel {
  const __hip_bfloat16* xl;
  const __hip_bfloat16* xr;
  const int* off; const int* cnt; const int* srce;
  const float* att; float* acc;
  int n; int self_loop;
};

__device__ inline float gat_wave(const GatRel& r, int d, int lane) {
  ushort4 ur = *reinterpret_cast<const ushort4*>(r.xr + (size_t)d * DDIM + 4 * lane);
  float c0 = b2f(ur.x), c1 = b2f(ur.y), c2 = b2f(ur.z), c3 = b2f(ur.w);
  float4 at = *reinterpret_cast<const float4*>(r.att + 4 * lane);
  const char* xlb = reinterpret_cast<const char*>(r.xl) + 8 * lane;  // 4*lane bf16

  float denA = 0.f, a0 = 0.f, a1 = 0.f, a2 = 0.f, a3 = 0.f;
  float denB = 0.f, b0 = 0.f, b1 = 0.f, b2v = 0.f, b3 = 0.f;

#define EBODYA(ux) {                                                            \
    float x0 = b2f(ux.x), x1 = b2f(ux.y), x2 = b2f(ux.z), x3 = b2f(ux.w);       \
    float t0 = x0 + c0; t0 = fmaxf(t0, 0.2f * t0);                              \
    float t1 = x1 + c1; t1 = fmaxf(t1, 0.2f * t1);                              \
    float t2 = x2 + c2; t2 = fmaxf(t2, 0.2f * t2);                              \
    float t3 = x3 + c3; t3 = fmaxf(t3, 0.2f * t3);                              \
    float pp = t0 * at.x + t1 * at.y + t2 * at.z + t3 * at.w;                   \
    pp = rowsum16(pp);                                                          \
    float ex = __expf(pp);                                                      \
    denA += ex;                                                                 \
    a0 = fmaf(ex, x0, a0); a1 = fmaf(ex, x1, a1);                               \
    a2 = fmaf(ex, x2, a2); a3 = fmaf(ex, x3, a3);                               \
  }
#define EBODYB(ux) {                                                            \
    float x0 = b2f(ux.x), x1 = b2f(ux.y), x2 = b2f(ux.z), x3 = b2f(ux.w);       \
    float t0 = x0 + c0; t0 = fmaxf(t0, 0.2f * t0);                              \
    float t1 = x1 + c1; t1 = fmaxf(t1, 0.2f * t1);                              \
    float t2 = x2 + c2; t2 = fmaxf(t2, 0.2f * t2);                              \
    float t3 = x3 + c3; t3 = fmaxf(t3, 0.2f * t3);                              \
    float pp = t0 * at.x + t1 * at.y + t2 * at.z + t3 * at.w;                   \
    pp = rowsum16(pp);                                                          \
    float ex = __expf(pp);                                                      \
    denB += ex;                                                                 \
    b0 = fmaf(ex, x0, b0); b1 = fmaf(ex, x1, b1);                               \
    b2v = fmaf(ex, x2, b2v); b3 = fmaf(ex, x3, b3);                             \
  }
#define ELOADB(o_) *reinterpret_cast<const ushort4*>(xlb + (o_))

  if (r.self_loop) { ushort4 ux = ELOADB(d * ROWB); EBODYA(ux) }
  int cnt = r.cnt[d];
  int beg = r.off[d];
  for (int jb = 0; jb < cnt; jb += 64) {
    int jj = jb + lane; if (jj > cnt - 1) jj = cnt - 1;
    int srcv = r.srce[beg + jj];           // coalesced chunk of edge byte-offsets
    int lim = cnt - jb; if (lim > 64) lim = 64;
    int u = 0;
    for (; u + 4 <= lim; u += 4) {         // 4 gathers in flight per step
      int s0 = __shfl(srcv, u), s1 = __shfl(srcv, u + 1);
      int s2 = __shfl(srcv, u + 2), s3 = __shfl(srcv, u + 3);
      ushort4 ux0 = ELOADB(s0); ushort4 ux1 = ELOADB(s1);
      ushort4 ux2 = ELOADB(s2); ushort4 ux3 = ELOADB(s3);
      EBODYA(ux0) EBODYB(ux1) EBODYA(ux2) EBODYB(ux3)
    }
    for (; u < lim; ++u) {
      int s = __shfl(srcv, u);
      ushort4 ux = ELOADB(s); EBODYA(ux)
    }
  }
#undef EBODYA
#undef EBODYB
#undef ELOADB

  float den = denA + denB;
  float p0 = a0 + b0, p1 = a1 + b1, p2 = a2 + b2v, p3 = a3 + b3;
  float inv = (den > 0.f) ? 1.0f / den : 0.f;
  p0 *= inv; p1 *= inv; p2 *= inv; p3 *= inv;
  p0 += __shfl_xor(p0, 16); p0 += __shfl_xor(p0, 32);
  p1 += __shfl_xor(p1, 16); p1 += __shfl_xor(p1, 32);
  p2 += __shfl_xor(p2, 16); p2 += __shfl_xor(p2, 32);
  p3 += __shfl_xor(p3, 16); p3 += __shfl_xor(p3, 32);
  int srcl = lane >> 2;
  float v0 = __shfl(p0, srcl);
  float v1 = __shfl(p1, srcl);
  float v2 = __shfl(p2, srcl);
  float v3 = __shfl(p3, srcl);
  float val = (lane & 2) ? ((lane & 1) ? v3 : v2) : ((lane & 1) ? v1 : v0);
  return 0.25f * val;
}

// ---------------- finalize wave body ----------------
struct FDesc {
  const float* accA; const float* accB;
  float* out;
  const float* bA; const float* bB; float scale;
  const float* g; const float* be;
  int n; unsigned key0, key1;
};

__device__ inline void finalize_wave(const FDesc& f, int d, int lane, float agg) {
  unsigned idx = (unsigned)d * 64u + (unsigned)lane;
  float bias = f.bA[lane] + (f.bB ? f.bB[lane] : 0.f);
  float pre = f.scale * (agg + bias);
  pre = (pre > 0.f) ? pre : expm1f(pre);  // elu
  pre += f.out[idx];                      // + proj (bias already added)
  float mu = pre;
#pragma unroll
  for (int off = 32; off; off >>= 1) mu += __shfl_xor(mu, off);
  mu *= (1.0f / 64.0f);
  float dv = pre - mu;
  float var = dv * dv;
#pragma unroll
  for (int off = 32; off; off >>= 1) var += __shfl_xor(var, off);
  var *= (1.0f / 64.0f);
  float y = dv * rsqrtf(var + 1e-5f) * f.g[lane] + f.be[lane];
  unsigned o0, o1;
  tf2x32(f.key0, f.key1, 0u, idx, o0, o1);
  unsigned bits = o0 ^ o1;
  float u = __uint_as_float((bits >> 9) | 0x3f800000u) - 1.0f;
  y = (u < 0.8f) ? y / 0.8f : 0.0f;
  f.out[idx] = y;
}

// ---------------- fused GAT + finalize ----------------
__global__ __launch_bounds__(256) void gat_fused(
    GatRel rsub, GatRel rshr, GatRel rprod,
    FDesc frxn, FDesc fmet, int rxnBlocks) {
  __shared__ float lv[4][64];
  int wave = threadIdx.x >> 6, lane = threadIdx.x & 63;
  if (blockIdx.x < rxnBlocks) {
    int d = blockIdx.x * 2 + (wave >> 1);
    const GatRel& r = (wave & 1) ? rshr : rsub;
    float val = 0.f;
    if (d < rsub.n) val = gat_wave(r, d, lane);
    lv[wave][lane] = val;
    __syncthreads();
    if ((wave & 1) == 0 && d < rsub.n) {
      float agg = lv[wave][lane] + lv[wave + 1][lane];
      finalize_wave(frxn, d, lane, agg);
    }
  } else {
    int d = (blockIdx.x - rxnBlocks) * 4 + wave;
    if (d >= rprod.n) return;
    float agg = gat_wave(rprod, d, lane);
    finalize_wave(fmet, d, lane, agg);
  }
}

// ---------------- fallback kernels (small-ws path) ----------------
__global__ __launch_bounds__(256) void gat3(GatRel r0, GatRel r1, GatRel r2) {
  int gidx = blockIdx.x * 4 + (threadIdx.x >> 6);
  int lane = threadIdx.x & 63;
  GatRel r; int d;
  if (gidx < r0.n) { r = r0; d = gidx; }
  else if (gidx < r0.n + r1.n) { r = r1; d = gidx - r0.n; }
  else if (gidx < r0.n + r1.n + r2.n) { r = r2; d = gidx - r0.n - r1.n; }
  else return;
  r.acc[(size_t)d * 64 + lane] = gat_wave(r, d, lane);
}

__global__ __launch_bounds__(256) void finalize2(FDesc f0, FDesc f1) {
  int gidx = blockIdx.x * 4 + (threadIdx.x >> 6);
  int lane = threadIdx.x & 63;
  FDesc f; int d;
  if (gidx < f0.n) { f = f0; d = gidx; }
  else if (gidx < f0.n + f1.n) { f = f1; d = gidx - f0.n; }
  else return;
  unsigned idx = (unsigned)d * 64u + (unsigned)lane;
  float agg = f.accA[idx] + (f.accB ? f.accB[idx] : 0.f);
  finalize_wave(f, d, lane, agg);
}

// ---------------- launch ----------------
extern "C" void kernel_launch(void* const* d_in, const int* in_sizes, int n_in,
                              void* d_out, int out_size, void* d_ws, size_t ws_size,
                              hipStream_t stream) {
  const float* x_met = (const float*)d_in[0];
  const float* x_rxn = (const float*)d_in[1];
  const int* sub_src = (const int*)d_in[2];
  const int* sub_dst = (const int*)d_in[3];
  const int* prod_src = (const int*)d_in[4];
  const int* prod_dst = (const int*)d_in[5];
  const int* shr_src = (const int*)d_in[6];
  const int* shr_dst = (const int*)d_in[7];
  const float* Wl_sub = (const float*)d_in[8];
  const float* bl_sub = (const float*)d_in[9];
  const float* Wr_sub = (const float*)d_in[10];
  const float* br_sub = (const float*)d_in[11];
  const float* att_sub = (const float*)d_in[12];
  const float* b_sub = (const float*)d_in[13];
  const float* Wl_prod = (const float*)d_in[14];
  const float* bl_prod = (const float*)d_in[15];
  const float* Wr_prod = (const float*)d_in[16];
  const float* br_prod = (const float*)d_in[17];
  const float* att_prod = (const float*)d_in[18];
  const float* b_prod = (const float*)d_in[19];
  const float* Wl_shr = (const float*)d_in[20];
  const float* bl_shr = (const float*)d_in[21];
  const float* Wr_shr = (const float*)d_in[22];
  const float* br_shr = (const float*)d_in[23];
  const float* att_shr = (const float*)d_in[24];
  const float* b_shr = (const float*)d_in[25];
  const float* W_proj_rxn = (const float*)d_in[26];
  const float* b_proj_rxn = (const float*)d_in[27];
  const float* W_proj_met = (const float*)d_in[28];
  const float* b_proj_met = (const float*)d_in[29];
  const float* ln_rxn_g = (const float*)d_in[30];
  const float* ln_rxn_b = (const float*)d_in[31];
  const float* ln_met_g = (const float*)d_in[32];
  const float* ln_met_b = (const float*)d_in[33];

  const int E = in_sizes[2];  // 250000

  // workspace carve
  char* p = (char*)d_ws;
  auto take = [&](size_t b) { char* q = p; p += (b + 255) & ~(size_t)255; return q; };
  __hip_bfloat16* xmb = (__hip_bfloat16*)take((size_t)NMET * DDIM * 2);
  __hip_bfloat16* xrb = (__hip_bfloat16*)take((size_t)NRXN * DDIM * 2);
  __hip_bfloat16* wt[8];
  for (int i = 0; i < 6; ++i) wt[i] = (__hip_bfloat16*)take(256 * 256 * 2);
  for (int i = 6; i < 8; ++i) wt[i] = (__hip_bfloat16*)take(64 * 256 * 2);
  float* acc_sub = (float*)take((size_t)NRXN * CDIM * 4);
  float* acc_shr = (float*)take((size_t)NRXN * CDIM * 4);
  float* acc_met = (float*)take((size_t)NMET * CDIM * 4);
  int* cnt_sub = (int*)take((size_t)NRXN * 4 + (size_t)NRXN * 4 + (size_t)NMET * 4 + 16);
  int* cnt_shr = cnt_sub + NRXN;
  int* cnt_prod = cnt_shr + NRXN;
  int* cursors = cnt_prod + NMET;
  int* off_sub = (int*)take((size_t)NRXN * 4);
  int* off_shr = (int*)take((size_t)NRXN * 4);
  int* off_prod = (int*)take((size_t)NMET * 4);
  int* cur_sub = (int*)take((size_t)NRXN * 4);
  int* cur_shr = (int*)take((size_t)NRXN * 4);
  int* cur_prod = (int*)take((size_t)NMET * 4);
  int* srce_sub = (int*)take((size_t)E * 4);
  int* srce_shr = (int*)take((size_t)E * 4);
  int* srce_prod = (int*)take((size_t)E * 4);

  size_t met_b = (size_t)NMET * DDIM * 2, rxn_b = (size_t)NRXN * DDIM * 2;
  size_t used = (size_t)(p - (char*)d_ws);
  bool big = (ws_size >= used + 3 * met_b + 3 * rxn_b + 4096);

  __hip_bfloat16 *xl_sub, *xr_sub, *xl_shr, *xr_shr, *xl_prod, *xr_prod;
  if (big) {
    xl_sub = (__hip_bfloat16*)take(met_b);   // sub: src=met
    xr_sub = (__hip_bfloat16*)take(rxn_b);
    xl_shr = (__hip_bfloat16*)take(rxn_b);
    xr_shr = (__hip_bfloat16*)take(rxn_b);
    xl_prod = (__hip_bfloat16*)take(rxn_b);  // prod: src=rxn
    xr_prod = (__hip_bfloat16*)take(met_b);
  } else {
    __hip_bfloat16* xa = (__hip_bfloat16*)take(rxn_b);
    __hip_bfloat16* xb = (__hip_bfloat16*)take(rxn_b);
    xl_sub = xl_shr = xl_prod = xa;
    xr_sub = xr_shr = xr_prod = xb;
  }

  float* out_rxn = (float*)d_out;
  float* out_met = out_rxn + (size_t)NRXN * CDIM;

  // host-side threefry split (partitionable): subkey i = tf(key, (0, i))
  unsigned k1_0, k1_1, k2_0, k2_1;
  tf2x32(0u, 1u, 0u, 0u, k1_0, k1_1);
  tf2x32(0u, 1u, 0u, 1u, k2_0, k2_1);

  dim3 blk(256);
  const int histB = (E + 255) / 256;

  // ---- memset -> fused prep+hist ----
  hipMemsetAsync(cnt_sub, 0, ((size_t)(NRXN + NRXN + NMET) + 4) * 4, stream);
  prep_all<<<3 * histB + CVT_A_BLK + CVT_B_BLK + 512, blk, 0, stream>>>(
      x_met, xmb, x_rxn, xrb,
      Wl_sub, Wr_sub, Wl_shr, Wr_shr, Wl_prod, Wr_prod, W_proj_rxn, W_proj_met,
      wt[0], wt[1], wt[2], wt[3], wt[4], wt[5], wt[6], wt[7],
      sub_dst, shr_dst, prod_dst, E, cnt_sub, cnt_shr, cnt_prod, histB);
  alloc3<<<dim3((NRXN + 255) / 256, 3), blk, 0, stream>>>(
      cnt_sub, cnt_shr, cnt_prod, off_sub, off_shr, off_prod,
      cur_sub, cur_shr, cur_prod, cursors, NRXN, NRXN, NMET);

  ScatArgs sa;
  sa.s0 = sub_src; sa.d0 = sub_dst; sa.s1 = shr_src; sa.d1 = shr_dst;
  sa.s2 = prod_src; sa.d2 = prod_dst; sa.E = E;
  sa.u0 = cur_sub; sa.u1 = cur_shr; sa.u2 = cur_prod;
  sa.e0 = srce_sub; sa.e1 = srce_shr; sa.e2 = srce_prod;

  auto mk = [](const __hip_bfloat16* X, const __hip_bfloat16* W, const float* bias,
               __hip_bfloat16* Yb, float* Yf, int M, int N) {
    TDesc g; g.X = X; g.W = W; g.bias = bias; g.Yb = Yb; g.Yf = Yf;
    g.M = M; g.N = N; g.nt = (N + 127) / 128;
    g.blocks = ((M + 127) / 128) * g.nt;
    return g;
  };
  auto mkrel = [](const __hip_bfloat16* xl, const __hip_bfloat16* xr,
                  const int* off, const int* cnt, const int* srce,
                  const float* att, float* acc, int n, int sl) {
    GatRel r; r.xl = xl; r.xr = xr; r.off = off; r.cnt = cnt; r.srce = srce;
    r.att = att; r.acc = acc; r.n = n; r.self_loop = sl;
    return r;
  };
  GatRel rz{}; rz.n = 0;

  TDesc dsub_r  = mk(xrb, wt[1], br_sub,     xr_sub,  nullptr, NRXN, DDIM);
  TDesc dshr_l  = mk(xrb, wt[2], bl_shr,     xl_shr,  nullptr, NRXN, DDIM);
  TDesc dshr_r  = mk(xrb, wt[3], br_shr,     xr_shr,  nullptr, NRXN, DDIM);
  TDesc dprod_l = mk(xrb, wt[4], bl_prod,    xl_prod, nullptr, NRXN, DDIM);
  TDesc dproj_r = mk(xrb, wt[6], b_proj_rxn, nullptr, out_rxn, NRXN, CDIM);
  TDesc dsub_l  = mk(xmb, wt[0], bl_sub,     xl_sub,  nullptr, NMET, DDIM);
  TDesc dprod_m = mk(xmb, wt[5], br_prod,    xr_prod, nullptr, NMET, DDIM);
  TDesc dproj_m = mk(xmb, wt[7], b_proj_met, nullptr, out_met, NMET, CDIM);

  GatRel rsub = mkrel(xl_sub, xr_sub, off_sub, cnt_sub, srce_sub, att_sub, acc_sub, NRXN, 0);
  GatRel rshr = mkrel(xl_shr, xr_shr, off_shr, cnt_shr, srce_shr, att_shr, acc_shr, NRXN, 1);
  GatRel rprod = mkrel(xl_prod, xr_prod, off_prod, cnt_prod, srce_prod, att_prod, acc_met, NMET, 0);

  FDesc f0, f1;
  f0.accA = acc_sub; f0.accB = acc_shr; f0.out = out_rxn;
  f0.bA = b_sub; f0.bB = b_shr; f0.scale = 0.5f;
  f0.g = ln_rxn_g; f0.be = ln_rxn_b; f0.n = NRXN; f0.key0 = k1_0; f0.key1 = k1_1;
  f1.accA = acc_met; f1.accB = nullptr; f1.out = out_met;
  f1.bA = b_prod; f1.bB = nullptr; f1.scale = 1.0f;
  f1.g = ln_met_g; f1.be = ln_met_b; f1.n = NMET; f1.key0 = k2_0; f1.key1 = k2_1;

  if (big) {
    TD8 gd = {{dsub_r, dshr_l, dshr_r, dprod_l, dproj_r, dsub_l, dprod_m, dproj_m}};
    int tot = 0;
    for (int i = 0; i < 8; ++i) tot += gd.g[i].blocks;
    gemm_tiled8<<<tot + 3 * histB, blk, 0, stream>>>(gd, 8, tot, sa, histB);
    int rxnBlocks = (NRXN + 1) / 2;
    int metBlocks = (NMET + 3) / 4;
    gat_fused<<<rxnBlocks + metBlocks, blk, 0, stream>>>(
        rsub, rshr, rprod, f0, f1, rxnBlocks);
  } else {
    TD8 gd1 = {{dproj_r, dproj_m, dsub_l, dsub_r}};
    int t1 = gd1.g[0].blocks + gd1.g[1].blocks + gd1.g[2].blocks + gd1.g[3].blocks;
    gemm_tiled8<<<t1 + 3 * histB, blk, 0, stream>>>(gd1, 4, t1, sa, histB);
    gat3<<<(NRXN + 3) / 4, blk, 0, stream>>>(rsub, rz, rz);
    ScatArgs sz{}; sz.E = 0;
    TD8 gd2 = {{dshr_l, dshr_r}};
    int t2 = gd2.g[0].blocks + gd2.g[1].blocks;
    gemm_tiled8<<<t2, blk, 0, stream>>>(gd2, 2, t2, sz, 0);
    gat3<<<(NRXN + 3) / 4, blk, 0, stream>>>(rshr, rz, rz);
    TD8 gd3 = {{dprod_l, dprod_m}};
    int t3 = gd3.g[0].blocks + gd3.g[1].blocks;
    gemm_tiled8<<<t3, blk, 0, stream>>>(gd3, 2, t3, sz, 0);
    gat3<<<(NMET + 3) / 4, blk, 0, stream>>>(rprod, rz, rz);
    finalize2<<<(NRXN + NMET + 3) / 4, blk, 0, stream>>>(f0, f1);
  }
}

// Round 24
// 299.251 us; speedup vs baseline: 1.0041x; 1.0041x over previous
//
#include <hip/hip_runtime.h>
#include <hip/hip_bf16.h>
#include <stdint.h>

#define NMET 20000
#define NRXN 40000
#define DDIM 256
#define CDIM 64
#define ROWB 512   // bytes per feature row (256 bf16)

typedef __attribute__((ext_vector_type(8))) short bf16x8;
typedef __attribute__((ext_vector_type(4))) float f32x4;
typedef __attribute__((ext_vector_type(2))) float f32x2;

typedef __attribute__((address_space(1))) const void gvoid_t;
typedef __attribute__((address_space(3))) void lvoid_t;

// ---------------- threefry2x32 (exact JAX semantics) ----------------
__host__ __device__ inline void tf2x32(unsigned k0, unsigned k1,
                                       unsigned x0, unsigned x1,
                                       unsigned &o0, unsigned &o1) {
  unsigned ks2 = k0 ^ k1 ^ 0x1BD11BDAu;
#define TFR(r) { x0 += x1; x1 = (x1 << r) | (x1 >> (32 - r)); x1 ^= x0; }
  x0 += k0; x1 += k1;
  TFR(13) TFR(15) TFR(26) TFR(6)
  x0 += k1; x1 += ks2 + 1u;
  TFR(17) TFR(29) TFR(16) TFR(24)
  x0 += ks2; x1 += k0 + 2u;
  TFR(13) TFR(15) TFR(26) TFR(6)
  x0 += k0; x1 += k1 + 3u;
  TFR(17) TFR(29) TFR(16) TFR(24)
  x0 += k1; x1 += ks2 + 4u;
  TFR(13) TFR(15) TFR(26) TFR(6)
  x0 += ks2; x1 += k0 + 5u;
#undef TFR
  o0 = x0; o1 = x1;
}

__device__ inline unsigned short f2bbits(float f) {
  __hip_bfloat16 h = __float2bfloat16(f);
  return *reinterpret_cast<unsigned short*>(&h);
}
__device__ inline float b2f(unsigned short u) {
  unsigned v = (unsigned)u << 16;
  return __uint_as_float(v);
}

// 16-lane row sum via DPP row_ror (VALU pipe, no DS): every lane gets the row total.
__device__ inline float rowsum16(float v) {
  int t;
  t = __builtin_amdgcn_update_dpp(0, __float_as_int(v), 0x128, 0xF, 0xF, false);  // row_ror:8
  v += __int_as_float(t);
  t = __builtin_amdgcn_update_dpp(0, __float_as_int(v), 0x124, 0xF, 0xF, false);  // row_ror:4
  v += __int_as_float(t);
  t = __builtin_amdgcn_update_dpp(0, __float_as_int(v), 0x122, 0xF, 0xF, false);  // row_ror:2
  v += __int_as_float(t);
  t = __builtin_amdgcn_update_dpp(0, __float_as_int(v), 0x121, 0xF, 0xF, false);  // row_ror:1
  v += __int_as_float(t);
  return v;
}

// ---------------- prep: hist3 + cvt(x_met) + cvt(x_rxn) + wtrans, one dispatch ----------------
#define CVT_A_BLK 2500   // NMET*DDIM/8/256
#define CVT_B_BLK 5000   // NRXN*DDIM/8/256
__global__ __launch_bounds__(256) void prep_all(
    const float* __restrict__ x_met, __hip_bfloat16* __restrict__ xmb,
    const float* __restrict__ x_rxn, __hip_bfloat16* __restrict__ xrb,
    const float* w0, const float* w1, const float* w2, const float* w3,
    const float* w4, const float* w5, const float* w6, const float* w7,
    __hip_bfloat16* o0, __hip_bfloat16* o1, __hip_bfloat16* o2, __hip_bfloat16* o3,
    __hip_bfloat16* o4, __hip_bfloat16* o5, __hip_bfloat16* o6, __hip_bfloat16* o7,
    const int* __restrict__ hd0, const int* __restrict__ hd1, const int* __restrict__ hd2,
    int E, int* __restrict__ hc0, int* __restrict__ hc1, int* __restrict__ hc2,
    int histB) {
  __shared__ float ts[32][33];
  int bid = blockIdx.x;
  // ---- hist role (first 3*histB blocks) ----
  if (bid < 3 * histB) {
    int rel = bid / histB;
    int i = (bid - rel * histB) * 256 + threadIdx.x;
    if (i < E) {
      if (rel == 0) atomicAdd(&hc0[hd0[i]], 1);
      else if (rel == 1) atomicAdd(&hc1[hd1[i]], 1);
      else atomicAdd(&hc2[hd2[i]], 1);
    }
    return;
  }
  bid -= 3 * histB;
  if (bid < CVT_A_BLK + CVT_B_BLK) {
    const float* in; __hip_bfloat16* out; int n;
    if (bid < CVT_A_BLK) { in = x_met; out = xmb; n = NMET * DDIM; }
    else { in = x_rxn; out = xrb; n = NRXN * DDIM; bid -= CVT_A_BLK; }
    int i = (bid * 256 + threadIdx.x) * 8;
    if (i >= n) return;
    float4 va = *reinterpret_cast<const float4*>(in + i);
    float4 vb = *reinterpret_cast<const float4*>(in + i + 4);
    bf16x8 o;
    o[0] = (short)f2bbits(va.x); o[1] = (short)f2bbits(va.y);
    o[2] = (short)f2bbits(va.z); o[3] = (short)f2bbits(va.w);
    o[4] = (short)f2bbits(vb.x); o[5] = (short)f2bbits(vb.y);
    o[6] = (short)f2bbits(vb.z); o[7] = (short)f2bbits(vb.w);
    *reinterpret_cast<bf16x8*>(out + i) = o;
    return;
  }
  int t = bid - (CVT_A_BLK + CVT_B_BLK);
  int z = t >> 6, tt = t & 63;
  const float* w; __hip_bfloat16* o; int Ncols;
  switch (z) {
    case 0: w = w0; o = o0; Ncols = 256; break;
    case 1: w = w1; o = o1; Ncols = 256; break;
    case 2: w = w2; o = o2; Ncols = 256; break;
    case 3: w = w3; o = o3; Ncols = 256; break;
    case 4: w = w4; o = o4; Ncols = 256; break;
    case 5: w = w5; o = o5; Ncols = 256; break;
    case 6: w = w6; o = o6; Ncols = 64; break;
    default: w = w7; o = o7; Ncols = 64; break;
  }
  int ntile = Ncols / 32;
  if (tt >= ntile * 8) return;  // K=256 -> 8 k-tiles
  int tn = tt % ntile, tk = tt / ntile;
  int tx = threadIdx.x & 31, ty = threadIdx.x >> 5;
#pragma unroll
  for (int r = ty; r < 32; r += 8)
    ts[r][tx] = w[(size_t)(tk * 32 + r) * Ncols + tn * 32 + tx];
  __syncthreads();
#pragma unroll
  for (int r = ty; r < 32; r += 8)
    o[(size_t)(tn * 32 + r) * 256 + tk * 32 + tx] = __float2bfloat16(ts[tx][r]);
}

// ---------------- scatter args (fused into gemm dispatch, tail blocks) ----------------
struct ScatArgs {
  const int *s0, *d0, *s1, *d1, *s2, *d2;
  int E;
  int *u0, *u1, *u2, *e0, *e1, *e2;
};

// ---------------- tiled multi-GEMM + tail scatter: 128x128 tile, BK=64, LDS + XCD swizzle ----------------
struct TDesc {
  const __hip_bfloat16* X;   // [M,256]
  const __hip_bfloat16* W;   // Wt[N,256]
  const float* bias;
  __hip_bfloat16* Yb;        // bf16 out (or null)
  float* Yf;                 // f32 out (or null)
  int M, N, nt, blocks;      // nt = ceil(N/128), blocks = ceil(M/128)*nt
};
struct TD8 { TDesc g[8]; };

__global__ __launch_bounds__(256) void gemm_tiled8(TD8 gd, int ng, int total,
                                                   ScatArgs sa, int scatB) {
  __shared__ __align__(16) char As[16384];   // A tile [128][64] bf16, swizzled groups
  __shared__ __align__(16) char Bs[16384];   // B tile [128][64] bf16
  int b = blockIdx.x;
  // ---- scatter role: TAIL blocks (launch after GEMM fills the machine) ----
  if (b >= total) {
    int sb = b - total;
    int rel = sb / scatB;
    int i = (sb - rel * scatB) * 256 + threadIdx.x;
    if (i < sa.E) {
      if (rel == 0)      { int pos = atomicAdd(&sa.u0[sa.d0[i]], 1); sa.e0[pos] = sa.s0[i] * ROWB; }
      else if (rel == 1) { int pos = atomicAdd(&sa.u1[sa.d1[i]], 1); sa.e1[pos] = sa.s1[i] * ROWB; }
      else               { int pos = atomicAdd(&sa.u2[sa.d2[i]], 1); sa.e2[pos] = sa.s2[i] * ROWB; }
    }
    return;
  }
  // T1: bijective XCD-chunked remap (m204 form) over the gemm block range.
  int q = total >> 3, r = total & 7;
  int xcd = b & 7, idx = b >> 3;
  int bid = (xcd < r) ? (xcd * (q + 1) + idx)
                      : (r * (q + 1) + (xcd - r) * q + idx);
  int di = 0;
  while (di < ng && bid >= gd.g[di].blocks) { bid -= gd.g[di].blocks; ++di; }
  if (di >= ng) return;
  TDesc g = gd.g[di];
  int mrow = bid / g.nt, ntile = bid - mrow * g.nt;
  int m0 = mrow * 128, n0 = ntile * 128;
  int tid = threadIdx.x, wave = tid >> 6, lane = tid & 63;
  int lr = lane & 15, lk = lane >> 4;
  int wm = wave >> 1, wn = wave & 1;
  int brows = g.N - n0; if (brows > 128) brows = 128;
  int bch = brows >> 3;               // B chunks of 8 rows (1024B)
  int lrow = lane >> 3;               // row within chunk (0..7)
  int gsw = ((lane & 7) ^ lrow) * 8;  // inverse-swizzled source col (bf16) within 64

  f32x4 acc[4][4] = {};
  for (int kt = 0; kt < 4; ++kt) {
    for (int c = wave; c < 16; c += 4) {
      int row = m0 + c * 8 + lrow;
      if (row > g.M - 1) row = g.M - 1;
      const void* src = g.X + (size_t)row * DDIM + kt * 64 + gsw;
      __builtin_amdgcn_global_load_lds((gvoid_t*)src, (lvoid_t*)(As + c * 1024), 16, 0, 0);
    }
    for (int c = wave; c < bch; c += 4) {
      int row = n0 + c * 8 + lrow;
      const void* src = g.W + (size_t)row * DDIM + kt * 64 + gsw;
      __builtin_amdgcn_global_load_lds((gvoid_t*)src, (lvoid_t*)(Bs + c * 1024), 16, 0, 0);
    }
    __syncthreads();
#pragma unroll
    for (int kk = 0; kk < 2; ++kk) {
      bf16x8 a[4], b2[4];
#pragma unroll
      for (int m = 0; m < 4; ++m) {
        int row = wm * 64 + m * 16 + lr;
        int grp = (kk * 4 + lk) ^ (lr & 7);
        a[m] = *reinterpret_cast<const bf16x8*>(As + row * 128 + grp * 16);
      }
#pragma unroll
      for (int n = 0; n < 4; ++n) {
        int row = wn * 64 + n * 16 + lr;
        int grp = (kk * 4 + lk) ^ (lr & 7);
        b2[n] = *reinterpret_cast<const bf16x8*>(Bs + row * 128 + grp * 16);
      }
#pragma unroll
      for (int m = 0; m < 4; ++m)
#pragma unroll
        for (int n = 0; n < 4; ++n)
          acc[m][n] = __builtin_amdgcn_mfma_f32_16x16x32_bf16(a[m], b2[n], acc[m][n], 0, 0, 0);
    }
    __syncthreads();
  }
  bool isb = (g.Yb != nullptr);
#pragma unroll
  for (int m = 0; m < 4; ++m) {
#pragma unroll
    for (int rr = 0; rr < 4; ++rr) {
      int row = m0 + wm * 64 + m * 16 + lk * 4 + rr;
      if (row >= g.M) continue;
#pragma unroll
      for (int n = 0; n < 4; ++n) {
        int cg = n0 + wn * 64 + n * 16 + lr;
        if (cg >= g.N) continue;
        float v = acc[m][n][rr] + g.bias[cg];
        if (isb) g.Yb[(size_t)row * g.N + cg] = __float2bfloat16(v);
        else     g.Yf[(size_t)row * g.N + cg] = v;
      }
    }
  }
}

// ---------------- range allocation via atomic cursor ----------------
__global__ __launch_bounds__(256) void alloc3(
    const int* __restrict__ c0, const int* __restrict__ c1, const int* __restrict__ c2,
    int* __restrict__ o0, int* __restrict__ o1, int* __restrict__ o2,
    int* __restrict__ u0, int* __restrict__ u1, int* __restrict__ u2,
    int* __restrict__ cursors, int n0, int n1, int n2) {
  int rel = blockIdx.y;
  int i = blockIdx.x * 256 + threadIdx.x;
  const int* c = (rel == 0) ? c0 : (rel == 1) ? c1 : c2;
  int* o = (rel == 0) ? o0 : (rel == 1) ? o1 : o2;
  int* u = (rel == 0) ? u0 : (rel == 1) ? u1 : u2;
  int n = (rel == 0) ? n0 : (rel == 1) ? n1 : n2;
  if (i >= n) return;
  int cc = c[i];
  int pos = atomicAdd(&cursors[rel], cc);
  o[i] = pos; u[i] = pos;
}

// ---------------- GAT wave body ----------------
// No-max softmax: scores bounded (|p| < ~6) so exp(p) is fp32-safe; identical result.
// DPP rowsum16 for the score reduce; packed-FP32 (float2) channel math for pk ops.
struct GatRel {
  const __hip_bfloat16* xl;
  const __hip_bfloat16* xr;
  const int* off; const int* cnt; const int* srce;
  const float* att; float* acc;
  int n; int self_loop;
};

__device__ inline float gat_wave(const GatRel& r, int d, int lane) {
  ushort4 ur = *reinterpret_cast<const ushort4*>(r.xr + (size_t)d * DDIM + 4 * lane);
  f32x2 c01 = {b2f(ur.x), b2f(ur.y)};
  f32x2 c23 = {b2f(ur.z), b2f(ur.w)};
  float4 at = *reinterpret_cast<const float4*>(r.att + 4 * lane);
  f32x2 at01 = {at.x, at.y}, at23 = {at.z, at.w};
  const char* xlb = reinterpret_cast<const char*>(r.xl) + 8 * lane;  // 4*lane bf16

  float denA = 0.f, denB = 0.f;
  f32x2 aA01 = {0.f, 0.f}, aA23 = {0.f, 0.f};
  f32x2 aB01 = {0.f, 0.f}, aB23 = {0.f, 0.f};

#define EBODYA(ux) {                                                            \
    f32x2 x01 = {b2f(ux.x), b2f(ux.y)};                                         \
    f32x2 x23 = {b2f(ux.z), b2f(ux.w)};                                         \
    f32x2 t01 = x01 + c01;                                                      \
    f32x2 t23 = x23 + c23;                                                      \
    f32x2 s01 = t01 * 0.2f;                                                     \
    f32x2 s23 = t23 * 0.2f;                                                     \
    t01.x = fmaxf(t01.x, s01.x); t01.y = fmaxf(t01.y, s01.y);                   \
    t23.x = fmaxf(t23.x, s23.x); t23.y = fmaxf(t23.y, s23.y);                   \
    f32x2 pv = t01 * at01;                                                      \
    pv = t23 * at23 + pv;                                                       \
    float pp = pv.x + pv.y;                                                     \
    pp = rowsum16(pp);                                                          \
    float ex = __expf(pp);                                                      \
    denA += ex;                                                                 \
    f32x2 ex2 = {ex, ex};                                                       \
    aA01 = ex2 * x01 + aA01;                                                    \
    aA23 = ex2 * x23 + aA23;                                                    \
  }
#define EBODYB(ux) {                                                            \
    f32x2 x01 = {b2f(ux.x), b2f(ux.y)};                                         \
    f32x2 x23 = {b2f(ux.z), b2f(ux.w)};                                         \
    f32x2 t01 = x01 + c01;                                                      \
    f32x2 t23 = x23 + c23;                                                      \
    f32x2 s01 = t01 * 0.2f;                                                     \
    f32x2 s23 = t23 * 0.2f;                                                     \
    t01.x = fmaxf(t01.x, s01.x); t01.y = fmaxf(t01.y, s01.y);                   \
    t23.x = fmaxf(t23.x, s23.x); t23.y = fmaxf(t23.y, s23.y);                   \
    f32x2 pv = t01 * at01;                                                      \
    pv = t23 * at23 + pv;                                                       \
    float pp = pv.x + pv.y;                                                     \
    pp = rowsum16(pp);                                                          \
    float ex = __expf(pp);                                                      \
    denB += ex;                                                                 \
    f32x2 ex2 = {ex, ex};                                                       \
    aB01 = ex2 * x01 + aB01;                                                    \
    aB23 = ex2 * x23 + aB23;                                                    \
  }
#define ELOADB(o_) *reinterpret_cast<const ushort4*>(xlb + (o_))

  if (r.self_loop) { ushort4 ux = ELOADB(d * ROWB); EBODYA(ux) }
  int cnt = r.cnt[d];
  int beg = r.off[d];
  for (int jb = 0; jb < cnt; jb += 64) {
    int jj = jb + lane; if (jj > cnt - 1) jj = cnt - 1;
    int srcv = r.srce[beg + jj];           // coalesced chunk of edge byte-offsets
    int lim = cnt - jb; if (lim > 64) lim = 64;
    int u = 0;
    for (; u + 4 <= lim; u += 4) {         // 4 gathers in flight per step
      int s0 = __shfl(srcv, u), s1 = __shfl(srcv, u + 1);
      int s2 = __shfl(srcv, u + 2), s3 = __shfl(srcv, u + 3);
      ushort4 ux0 = ELOADB(s0); ushort4 ux1 = ELOADB(s1);
      ushort4 ux2 = ELOADB(s2); ushort4 ux3 = ELOADB(s3);
      EBODYA(ux0) EBODYB(ux1) EBODYA(ux2) EBODYB(ux3)
    }
    for (; u < lim; ++u) {
      int s = __shfl(srcv, u);
      ushort4 ux = ELOADB(s); EBODYA(ux)
    }
  }
#undef EBODYA
#undef EBODYB
#undef ELOADB

  float den = denA + denB;
  f32x2 p01 = aA01 + aB01, p23 = aA23 + aB23;
  float inv = (den > 0.f) ? 1.0f / den : 0.f;
  float p0 = p01.x * inv, p1 = p01.y * inv, p2 = p23.x * inv, p3 = p23.y * inv;
  p0 += __shfl_xor(p0, 16); p0 += __shfl_xor(p0, 32);
  p1 += __shfl_xor(p1, 16); p1 += __shfl_xor(p1, 32);
  p2 += __shfl_xor(p2, 16); p2 += __shfl_xor(p2, 32);
  p3 += __shfl_xor(p3, 16); p3 += __shfl_xor(p3, 32);
  int srcl = lane >> 2;
  float v0 = __shfl(p0, srcl);
  float v1 = __shfl(p1, srcl);
  float v2 = __shfl(p2, srcl);
  float v3 = __shfl(p3, srcl);
  float val = (lane & 2) ? ((lane & 1) ? v3 : v2) : ((lane & 1) ? v1 : v0);
  return 0.25f * val;
}

// ---------------- finalize wave body ----------------
struct FDesc {
  const float* accA; const float* accB;
  float* out;
  const float* bA; const float* bB; float scale;
  const float* g; const float* be;
  int n; unsigned key0, key1;
};

__device__ inline void finalize_wave(const FDesc& f, int d, int lane, float agg) {
  unsigned idx = (unsigned)d * 64u + (unsigned)lane;
  float bias = f.bA[lane] + (f.bB ? f.bB[lane] : 0.f);
  float pre = f.scale * (agg + bias);
  pre = (pre > 0.f) ? pre : expm1f(pre);  // elu
  pre += f.out[idx];                      // + proj (bias already added)
  float mu = pre;
#pragma unroll
  for (int off = 32; off; off >>= 1) mu += __shfl_xor(mu, off);
  mu *= (1.0f / 64.0f);
  float dv = pre - mu;
  float var = dv * dv;
#pragma unroll
  for (int off = 32; off; off >>= 1) var += __shfl_xor(var, off);
  var *= (1.0f / 64.0f);
  float y = dv * rsqrtf(var + 1e-5f) * f.g[lane] + f.be[lane];
  unsigned o0, o1;
  tf2x32(f.key0, f.key1, 0u, idx, o0, o1);
  unsigned bits = o0 ^ o1;
  float u = __uint_as_float((bits >> 9) | 0x3f800000u) - 1.0f;
  y = (u < 0.8f) ? y / 0.8f : 0.0f;
  f.out[idx] = y;
}

// ---------------- fused GAT + finalize ----------------
__global__ __launch_bounds__(256) void gat_fused(
    GatRel rsub, GatRel rshr, GatRel rprod,
    FDesc frxn, FDesc fmet, int rxnBlocks) {
  __shared__ float lv[4][64];
  int wave = threadIdx.x >> 6, lane = threadIdx.x & 63;
  if (blockIdx.x < rxnBlocks) {
    int d = blockIdx.x * 2 + (wave >> 1);
    const GatRel& r = (wave & 1) ? rshr : rsub;
    float val = 0.f;
    if (d < rsub.n) val = gat_wave(r, d, lane);
    lv[wave][lane] = val;
    __syncthreads();
    if ((wave & 1) == 0 && d < rsub.n) {
      float agg = lv[wave][lane] + lv[wave + 1][lane];
      finalize_wave(frxn, d, lane, agg);
    }
  } else {
    int d = (blockIdx.x - rxnBlocks) * 4 + wave;
    if (d >= rprod.n) return;
    float agg = gat_wave(rprod, d, lane);
    finalize_wave(fmet, d, lane, agg);
  }
}

// ---------------- fallback kernels (small-ws path) ----------------
__global__ __launch_bounds__(256) void gat3(GatRel r0, GatRel r1, GatRel r2) {
  int gidx = blockIdx.x * 4 + (threadIdx.x >> 6);
  int lane = threadIdx.x & 63;
  GatRel r; int d;
  if (gidx < r0.n) { r = r0; d = gidx; }
  else if (gidx < r0.n + r1.n) { r = r1; d = gidx - r0.n; }
  else if (gidx < r0.n + r1.n + r2.n) { r = r2; d = gidx - r0.n - r1.n; }
  else return;
  r.acc[(size_t)d * 64 + lane] = gat_wave(r, d, lane);
}

__global__ __launch_bounds__(256) void finalize2(FDesc f0, FDesc f1) {
  int gidx = blockIdx.x * 4 + (threadIdx.x >> 6);
  int lane = threadIdx.x & 63;
  FDesc f; int d;
  if (gidx < f0.n) { f = f0; d = gidx; }
  else if (gidx < f0.n + f1.n) { f = f1; d = gidx - f0.n; }
  else return;
  unsigned idx = (unsigned)d * 64u + (unsigned)lane;
  float agg = f.accA[idx] + (f.accB ? f.accB[idx] : 0.f);
  finalize_wave(f, d, lane, agg);
}

// ---------------- launch ----------------
extern "C" void kernel_launch(void* const* d_in, const int* in_sizes, int n_in,
                              void* d_out, int out_size, void* d_ws, size_t ws_size,
                              hipStream_t stream) {
  const float* x_met = (const float*)d_in[0];
  const float* x_rxn = (const float*)d_in[1];
  const int* sub_src = (const int*)d_in[2];
  const int* sub_dst = (const int*)d_in[3];
  const int* prod_src = (const int*)d_in[4];
  const int* prod_dst = (const int*)d_in[5];
  const int* shr_src = (const int*)d_in[6];
  const int* shr_dst = (const int*)d_in[7];
  const float* Wl_sub = (const float*)d_in[8];
  const float* bl_sub = (const float*)d_in[9];
  const float* Wr_sub = (const float*)d_in[10];
  const float* br_sub = (const float*)d_in[11];
  const float* att_sub = (const float*)d_in[12];
  const float* b_sub = (const float*)d_in[13];
  const float* Wl_prod = (const float*)d_in[14];
  const float* bl_prod = (const float*)d_in[15];
  const float* Wr_prod = (const float*)d_in[16];
  const float* br_prod = (const float*)d_in[17];
  const float* att_prod = (const float*)d_in[18];
  const float* b_prod = (const float*)d_in[19];
  const float* Wl_shr = (const float*)d_in[20];
  const float* bl_shr = (const float*)d_in[21];
  const float* Wr_shr = (const float*)d_in[22];
  const float* br_shr = (const float*)d_in[23];
  const float* att_shr = (const float*)d_in[24];
  const float* b_shr = (const float*)d_in[25];
  const float* W_proj_rxn = (const float*)d_in[26];
  const float* b_proj_rxn = (const float*)d_in[27];
  const float* W_proj_met = (const float*)d_in[28];
  const float* b_proj_met = (const float*)d_in[29];
  const float* ln_rxn_g = (const float*)d_in[30];
  const float* ln_rxn_b = (const float*)d_in[31];
  const float* ln_met_g = (const float*)d_in[32];
  const float* ln_met_b = (const float*)d_in[33];

  const int E = in_sizes[2];  // 250000

  // workspace carve
  char* p = (char*)d_ws;
  auto take = [&](size_t b) { char* q = p; p += (b + 255) & ~(size_t)255; return q; };
  __hip_bfloat16* xmb = (__hip_bfloat16*)take((size_t)NMET * DDIM * 2);
  __hip_bfloat16* xrb = (__hip_bfloat16*)take((size_t)NRXN * DDIM * 2);
  __hip_bfloat16* wt[8];
  for (int i = 0; i < 6; ++i) wt[i] = (__hip_bfloat16*)take(256 * 256 * 2);
  for (int i = 6; i < 8; ++i) wt[i] = (__hip_bfloat16*)take(64 * 256 * 2);
  float* acc_sub = (float*)take((size_t)NRXN * CDIM * 4);
  float* acc_shr = (float*)take((size_t)NRXN * CDIM * 4);
  float* acc_met = (float*)take((size_t)NMET * CDIM * 4);
  int* cnt_sub = (int*)take((size_t)NRXN * 4 + (size_t)NRXN * 4 + (size_t)NMET * 4 + 16);
  int* cnt_shr = cnt_sub + NRXN;
  int* cnt_prod = cnt_shr + NRXN;
  int* cursors = cnt_prod + NMET;
  int* off_sub = (int*)take((size_t)NRXN * 4);
  int* off_shr = (int*)take((size_t)NRXN * 4);
  int* off_prod = (int*)take((size_t)NMET * 4);
  int* cur_sub = (int*)take((size_t)NRXN * 4);
  int* cur_shr = (int*)take((size_t)NRXN * 4);
  int* cur_prod = (int*)take((size_t)NMET * 4);
  int* srce_sub = (int*)take((size_t)E * 4);
  int* srce_shr = (int*)take((size_t)E * 4);
  int* srce_prod = (int*)take((size_t)E * 4);

  size_t met_b = (size_t)NMET * DDIM * 2, rxn_b = (size_t)NRXN * DDIM * 2;
  size_t used = (size_t)(p - (char*)d_ws);
  bool big = (ws_size >= used + 3 * met_b + 3 * rxn_b + 4096);

  __hip_bfloat16 *xl_sub, *xr_sub, *xl_shr, *xr_shr, *xl_prod, *xr_prod;
  if (big) {
    xl_sub = (__hip_bfloat16*)take(met_b);   // sub: src=met
    xr_sub = (__hip_bfloat16*)take(rxn_b);
    xl_shr = (__hip_bfloat16*)take(rxn_b);
    xr_shr = (__hip_bfloat16*)take(rxn_b);
    xl_prod = (__hip_bfloat16*)take(rxn_b);  // prod: src=rxn
    xr_prod = (__hip_bfloat16*)take(met_b);
  } else {
    __hip_bfloat16* xa = (__hip_bfloat16*)take(rxn_b);
    __hip_bfloat16* xb = (__hip_bfloat16*)take(rxn_b);
    xl_sub = xl_shr = xl_prod = xa;
    xr_sub = xr_shr = xr_prod = xb;
  }

  float* out_rxn = (float*)d_out;
  float* out_met = out_rxn + (size_t)NRXN * CDIM;

  // host-side threefry split (partitionable): subkey i = tf(key, (0, i))
  unsigned k1_0, k1_1, k2_0, k2_1;
  tf2x32(0u, 1u, 0u, 0u, k1_0, k1_1);
  tf2x32(0u, 1u, 0u, 1u, k2_0, k2_1);

  dim3 blk(256);
  const int histB = (E + 255) / 256;

  // ---- memset -> fused prep+hist ----
  hipMemsetAsync(cnt_sub, 0, ((size_t)(NRXN + NRXN + NMET) + 4) * 4, stream);
  prep_all<<<3 * histB + CVT_A_BLK + CVT_B_BLK + 512, blk, 0, stream>>>(
      x_met, xmb, x_rxn, xrb,
      Wl_sub, Wr_sub, Wl_shr, Wr_shr, Wl_prod, Wr_prod, W_proj_rxn, W_proj_met,
      wt[0], wt[1], wt[2], wt[3], wt[4], wt[5], wt[6], wt[7],
      sub_dst, shr_dst, prod_dst, E, cnt_sub, cnt_shr, cnt_prod, histB);
  alloc3<<<dim3((NRXN + 255) / 256, 3), blk, 0, stream>>>(
      cnt_sub, cnt_shr, cnt_prod, off_sub, off_shr, off_prod,
      cur_sub, cur_shr, cur_prod, cursors, NRXN, NRXN, NMET);

  ScatArgs sa;
  sa.s0 = sub_src; sa.d0 = sub_dst; sa.s1 = shr_src; sa.d1 = shr_dst;
  sa.s2 = prod_src; sa.d2 = prod_dst; sa.E = E;
  sa.u0 = cur_sub; sa.u1 = cur_shr; sa.u2 = cur_prod;
  sa.e0 = srce_sub; sa.e1 = srce_shr; sa.e2 = srce_prod;

  auto mk = [](const __hip_bfloat16* X, const __hip_bfloat16* W, const float* bias,
               __hip_bfloat16* Yb, float* Yf, int M, int N) {
    TDesc g; g.X = X; g.W = W; g.bias = bias; g.Yb = Yb; g.Yf = Yf;
    g.M = M; g.N = N; g.nt = (N + 127) / 128;
    g.blocks = ((M + 127) / 128) * g.nt;
    return g;
  };
  auto mkrel = [](const __hip_bfloat16* xl, const __hip_bfloat16* xr,
                  const int* off, const int* cnt, const int* srce,
                  const float* att, float* acc, int n, int sl) {
    GatRel r; r.xl = xl; r.xr = xr; r.off = off; r.cnt = cnt; r.srce = srce;
    r.att = att; r.acc = acc; r.n = n; r.self_loop = sl;
    return r;
  };
  GatRel rz{}; rz.n = 0;

  TDesc dsub_r  = mk(xrb, wt[1], br_sub,     xr_sub,  nullptr, NRXN, DDIM);
  TDesc dshr_l  = mk(xrb, wt[2], bl_shr,     xl_shr,  nullptr, NRXN, DDIM);
  TDesc dshr_r  = mk(xrb, wt[3], br_shr,     xr_shr,  nullptr, NRXN, DDIM);
  TDesc dprod_l = mk(xrb, wt[4], bl_prod,    xl_prod, nullptr, NRXN, DDIM);
  TDesc dproj_r = mk(xrb, wt[6], b_proj_rxn, nullptr, out_rxn, NRXN, CDIM);
  TDesc dsub_l  = mk(xmb, wt[0], bl_sub,     xl_sub,  nullptr, NMET, DDIM);
  TDesc dprod_m = mk(xmb, wt[5], br_prod,    xr_prod, nullptr, NMET, DDIM);
  TDesc dproj_m = mk(xmb, wt[7], b_proj_met, nullptr, out_met, NMET, CDIM);

  GatRel rsub = mkrel(xl_sub, xr_sub, off_sub, cnt_sub, srce_sub, att_sub, acc_sub, NRXN, 0);
  GatRel rshr = mkrel(xl_shr, xr_shr, off_shr, cnt_shr, srce_shr, att_shr, acc_shr, NRXN, 1);
  GatRel rprod = mkrel(xl_prod, xr_prod, off_prod, cnt_prod, srce_prod, att_prod, acc_met, NMET, 0);

  FDesc f0, f1;
  f0.accA = acc_sub; f0.accB = acc_shr; f0.out = out_rxn;
  f0.bA = b_sub; f0.bB = b_shr; f0.scale = 0.5f;
  f0.g = ln_rxn_g; f0.be = ln_rxn_b; f0.n = NRXN; f0.key0 = k1_0; f0.key1 = k1_1;
  f1.accA = acc_met; f1.accB = nullptr; f1.out = out_met;
  f1.bA = b_prod; f1.bB = nullptr; f1.scale = 1.0f;
  f1.g = ln_met_g; f1.be = ln_met_b; f1.n = NMET; f1.key0 = k2_0; f1.key1 = k2_1;

  if (big) {
    TD8 gd = {{dsub_r, dshr_l, dshr_r, dprod_l, dproj_r, dsub_l, dprod_m, dproj_m}};
    int tot = 0;
    for (int i = 0; i < 8; ++i) tot += gd.g[i].blocks;
    gemm_tiled8<<<tot + 3 * histB, blk, 0, stream>>>(gd, 8, tot, sa, histB);
    int rxnBlocks = (NRXN + 1) / 2;
    int metBlocks = (NMET + 3) / 4;
    gat_fused<<<rxnBlocks + metBlocks, blk, 0, stream>>>(
        rsub, rshr, rprod, f0, f1, rxnBlocks);
  } else {
    TD8 gd1 = {{dproj_r, dproj_m, dsub_l, dsub_r}};
    int t1 = gd1.g[0].blocks + gd1.g[1].blocks + gd1.g[2].blocks + gd1.g[3].blocks;
    gemm_tiled8<<<t1 + 3 * histB, blk, 0, stream>>>(gd1, 4, t1, sa, histB);
    gat3<<<(NRXN + 3) / 4, blk, 0, stream>>>(rsub, rz, rz);
    ScatArgs sz{}; sz.E = 0;
    TD8 gd2 = {{dshr_l, dshr_r}};
    int t2 = gd2.g[0].blocks + gd2.g[1].blocks;
    gemm_tiled8<<<t2, blk, 0, stream>>>(gd2, 2, t2, sz, 0);
    gat3<<<(NRXN + 3) / 4, blk, 0, stream>>>(rshr, rz, rz);
    TD8 gd3 = {{dprod_l, dprod_m}};
    int t3 = gd3.g[0].blocks + gd3.g[1].blocks;
    gemm_tiled8<<<t3, blk, 0, stream>>>(gd3, 2, t3, sz, 0);
    gat3<<<(NMET + 3) / 4, blk, 0, stream>>>(rprod, rz, rz);
    finalize2<<<(NRXN + NMET + 3) / 4, blk, 0, stream>>>(f0, f1);
  }
}